// Round 15
// baseline (138.770 us; speedup 1.0000x reference)
//
#include <hip/hip_runtime.h>

typedef __attribute__((ext_vector_type(8))) short short8;
typedef __attribute__((ext_vector_type(4))) float f32x4;
typedef __attribute__((ext_vector_type(2))) float f32x2;
typedef __attribute__((ext_vector_type(4))) unsigned int u32x4;

static __device__ __forceinline__ unsigned int fbits(float f) {
    union { float f; unsigned int u; } v; v.f = f; return v.u;
}
static __device__ __forceinline__ float bitsf(unsigned int u) {
    union { float f; unsigned int u; } v; v.u = u; return v.f;
}
static __device__ __forceinline__ unsigned int pkbf(float lo, float hi) {
    return __builtin_amdgcn_perm(fbits(hi), fbits(lo), 0x07060302u);
}
static __device__ __forceinline__ float leaky(float x) { return fmaxf(x, 0.01f * x); }
static __device__ __forceinline__ float rsqrt_nr(float x) {
    const float r = __builtin_amdgcn_rsqf(x);
    return r * (1.5f - (0.5f * x) * (r * r));
}
static __device__ __forceinline__ f32x2 pk_mul_v(f32x2 a, f32x2 b) {
    f32x2 d; asm("v_pk_mul_f32 %0, %1, %2" : "=v"(d) : "v"(a), "v"(b)); return d;
}
static __device__ __forceinline__ f32x2 pk_fma_v(f32x2 a, f32x2 b, f32x2 c) {
    f32x2 d; asm("v_pk_fma_f32 %0, %1, %2, %3" : "=v"(d) : "v"(a), "v"(b), "v"(c)); return d;
}

// ROUND 15: SCALE THE CONFIRMED LEVER. r14 broke the 53us floor (59 -> ~50) with
// 2 rows/lane on the all-MFMA r13 structure -- in-wave ILP across the serial
// L1..L4 MFMA chains is the bottleneck lever (occupancy FELL to 26% while wall
// dropped; wave-parallelism was never it). This round: 4 rows/lane = 16
// independent tile-chains/wave, preamble amortized 4x.
// launch_bounds (256,2): 256-VGPR cap so the allocator has room -- r4 taught
// that forced caps + arrays = scratch catastrophe; occupancy is proven
// irrelevant here. Tripwire stays WRITE_SIZE == 24.6 MB (no spills).
//
// Geometry: block=256 threads, 1024 rows (sets at base + {0,256,512,768} + tid).
// featlds 1025 rows x 32B (zero pad row 1024 for the last set's quad2/3 b128
// overread; inter-set overreads land in the next set's row 0 -- finite, and all
// k>=3 slots multiply ZERO A-weights). C-layout algebra and row ownership
// (lane keeps tile t==quad; wbase+16t+i15==tid) verified r10-r14.

struct Rot { float a0,a1,a2,c0,c1,c2,u0,u1,u2; };

static __device__ __forceinline__ Rot gs_feat(
    const float* __restrict__ vin, const float* __restrict__ win,
    int row, unsigned int* __restrict__ dst)
{
    const float v0 = vin[3*row+0], v1 = vin[3*row+1], v2 = vin[3*row+2];
    const float w0 = win[3*row+0], w1 = win[3*row+1], w2 = win[3*row+2];
    const float sv  = v0*v0 + v1*v1 + v2*v2;
    const float rnv = rsqrt_nr(sv);
    const float a0 = v0*rnv, a1 = v1*rnv, a2 = v2*rnv;            // v_on
    const float proj = w0*a0 + w1*a1 + w2*a2;
    const float o0 = w0 - proj*a0, o1 = w1 - proj*a1, o2 = w2 - proj*a2;
    const float sw  = o0*o0 + o1*o1 + o2*o2;
    const float rnw = rsqrt_nr(sw);
    const float c0 = o0*rnw, c1 = o1*rnw, c2 = o2*rnw;            // w_on
    const float u0 = a1*c2 - a2*c1;                               // u_on
    const float u1 = a2*c0 - a0*c2;
    const float u2 = a0*c1 - a1*c0;
    // feat row: u32 j = (k=j lo, k=j+16 hi); only j<3 lo nonzero
    *(u32x4*)(dst)     = (u32x4){ fbits(sv*rnv) >> 16, fbits(proj) >> 16,
                                  fbits(sw*rnw) >> 16, 0u };
    *(u32x4*)(dst + 4) = (u32x4){ 0u, 0u, 0u, 0u };
    return {a0,a1,a2,c0,c1,c2,u0,u1,u2};
}

// One 256-row set's fused L1..L4 chain. Uses enclosing scope: featlds, wbase,
// i15, quad, ko, fW1lo/hi, fW2lo/hi, fWd1lo/hi, cb*, w00..w23.
#define TILE_CHAIN(LB, YS0, YS1, YS2)                                              \
    {                                                                              \
        float y0k = 0.f, y1k = 0.f, y2k = 0.f;                                     \
        _Pragma("unroll")                                                          \
        for (int t = 0; t < 4; ++t) {                                              \
            const u32x4 bfr = *(const u32x4*)(                                     \
                &featlds[((LB) + wbase + 16*t + i15) * 8 + ko]);                   \
            const short8 featfrag = __builtin_bit_cast(short8, bfr);               \
            const f32x4 z1lo = __builtin_amdgcn_mfma_f32_16x16x32_bf16(            \
                fW1lo, featfrag, cb1lo, 0, 0, 0);                                  \
            const f32x4 z1hi = __builtin_amdgcn_mfma_f32_16x16x32_bf16(            \
                fW1hi, featfrag, cb1hi, 0, 0, 0);                                  \
            const float h1l0 = leaky(z1lo[0]), h1l1 = leaky(z1lo[1]);              \
            const float h1l2 = leaky(z1lo[2]), h1l3 = leaky(z1lo[3]);              \
            const float h1h0 = leaky(z1hi[0]), h1h1 = leaky(z1hi[1]);              \
            const float h1h2 = leaky(z1hi[2]), h1h3 = leaky(z1hi[3]);              \
            const short8 h1frag = __builtin_bit_cast(short8, (u32x4){              \
                pkbf(h1l0, h1h0), pkbf(h1l1, h1h1),                                \
                pkbf(h1l2, h1h2), pkbf(h1l3, h1h3) });                             \
            const f32x4 z2lo = __builtin_amdgcn_mfma_f32_16x16x32_bf16(            \
                fW2lo, h1frag, cb2lo, 0, 0, 0);                                    \
            const f32x4 z2hi = __builtin_amdgcn_mfma_f32_16x16x32_bf16(            \
                fW2hi, h1frag, cb2hi, 0, 0, 0);                                    \
            const short8 h2frag = __builtin_bit_cast(short8, (u32x4){              \
                pkbf(leaky(z2lo[0]) * h1l0, leaky(z2hi[0]) * h1h0),                \
                pkbf(leaky(z2lo[1]) * h1l1, leaky(z2hi[1]) * h1h1),                \
                pkbf(leaky(z2lo[2]) * h1l2, leaky(z2hi[2]) * h1h2),                \
                pkbf(leaky(z2lo[3]) * h1l3, leaky(z2hi[3]) * h1h3) });             \
            const f32x4 z3lo = __builtin_amdgcn_mfma_f32_16x16x32_bf16(            \
                fWd1lo, h2frag, cbd1lo, 0, 0, 0);                                  \
            const f32x4 z3hi = __builtin_amdgcn_mfma_f32_16x16x32_bf16(            \
                fWd1hi, h2frag, cbd1hi, 0, 0, 0);                                  \
            f32x2 h30, h31, h32, h33;                                              \
            h30.x = leaky(z3lo[0]); h30.y = leaky(z3hi[0]);                        \
            h31.x = leaky(z3lo[1]); h31.y = leaky(z3hi[1]);                        \
            h32.x = leaky(z3lo[2]); h32.y = leaky(z3hi[2]);                        \
            h33.x = leaky(z3lo[3]); h33.y = leaky(z3hi[3]);                        \
            f32x2 P0 = pk_mul_v(w00, h30);                                         \
            f32x2 P1 = pk_mul_v(w10, h30);                                         \
            f32x2 P2 = pk_mul_v(w20, h30);                                         \
            P0 = pk_fma_v(w01, h31, P0); P1 = pk_fma_v(w11, h31, P1);              \
            P2 = pk_fma_v(w21, h31, P2);                                           \
            P0 = pk_fma_v(w02, h32, P0); P1 = pk_fma_v(w12, h32, P1);              \
            P2 = pk_fma_v(w22, h32, P2);                                           \
            P0 = pk_fma_v(w03, h33, P0); P1 = pk_fma_v(w13, h33, P1);              \
            P2 = pk_fma_v(w23, h33, P2);                                           \
            float s0 = P0.x + P0.y, s1 = P1.x + P1.y, s2 = P2.x + P2.y;            \
            s0 += __shfl_xor(s0, 16); s0 += __shfl_xor(s0, 32);                    \
            s1 += __shfl_xor(s1, 16); s1 += __shfl_xor(s1, 32);                    \
            s2 += __shfl_xor(s2, 16); s2 += __shfl_xor(s2, 32);                    \
            if (quad == t) { y0k = s0; y1k = s1; y2k = s2; }                       \
        }                                                                          \
        YS0 = y0k; YS1 = y1k; YS2 = y2k;                                           \
    }

#define EMIT_OUT(R, Y0, Y1, Y2, ROW)                                               \
    out[3*(ROW) + 0] = fmaf(R.a0, Y0, fmaf(R.c0, Y1, fmaf(R.u0, Y2, gbs0)));       \
    out[3*(ROW) + 1] = fmaf(R.a1, Y0, fmaf(R.c1, Y1, fmaf(R.u1, Y2, gbs1)));       \
    out[3*(ROW) + 2] = fmaf(R.a2, Y0, fmaf(R.c2, Y1, fmaf(R.u2, Y2, gbs2)));

__global__ __launch_bounds__(256, 2) void aero_mfma(
    const float* __restrict__ vin, const float* __restrict__ win,
    const float* __restrict__ gW1, const float* __restrict__ gb1,
    const float* __restrict__ gW2, const float* __restrict__ gb2,
    const float* __restrict__ gWd1, const float* __restrict__ gbd1,
    const float* __restrict__ gWd2, const float* __restrict__ gbd2,
    const float* __restrict__ gbias,
    float* __restrict__ out, int nrows)
{
    __shared__ unsigned int featlds[1025 * 8];   // 1024 rows + 1 zero pad row

    const int tid   = threadIdx.x;
    const int i15   = tid & 15;
    const int quad  = (tid >> 4) & 3;
    const int wbase = tid & 192;               // wave's 64-row window (within a set)
    const int ko    = 4 * quad;

    const int base = blockIdx.x * 1024;
    int rowA = base + tid;        if (rowA >= nrows) rowA = nrows - 1;
    int rowB = base + 256 + tid;  if (rowB >= nrows) rowB = nrows - 1;
    int rowC = base + 512 + tid;  if (rowC >= nrows) rowC = nrows - 1;
    int rowD = base + 768 + tid;  if (rowD >= nrows) rowD = nrows - 1;

    // ---- preamble (once per wave, amortized over 4 rows/lane) ----
    unsigned int a1lo[4] = {0,0,0,0}, a1hi[4] = {0,0,0,0};
    if (quad == 0) {
        #pragma unroll
        for (int j = 0; j < 3; ++j) {
            a1lo[j] = fbits(gW1[i15 * 3 + j]) >> 16;          // (W1, 0) pair
            a1hi[j] = fbits(gW1[(16 + i15) * 3 + j]) >> 16;
        }
    }
    const short8 fW1lo = __builtin_bit_cast(short8, (u32x4){a1lo[0], a1lo[1], a1lo[2], a1lo[3]});
    const short8 fW1hi = __builtin_bit_cast(short8, (u32x4){a1hi[0], a1hi[1], a1hi[2], a1hi[3]});

    unsigned int a2lo[4], a2hi[4], a3lo[4], a3hi[4];
    {
        const float* p;
        p = gW2 + i15 * 32 + ko;
        { f32x4 xa = *(const f32x4*)p, xb = *(const f32x4*)(p + 16);
          #pragma unroll
          for (int j = 0; j < 4; ++j) a2lo[j] = pkbf(xa[j], xb[j]); }
        p = gW2 + (16 + i15) * 32 + ko;
        { f32x4 xa = *(const f32x4*)p, xb = *(const f32x4*)(p + 16);
          #pragma unroll
          for (int j = 0; j < 4; ++j) a2hi[j] = pkbf(xa[j], xb[j]); }
        p = gWd1 + i15 * 32 + ko;
        { f32x4 xa = *(const f32x4*)p, xb = *(const f32x4*)(p + 16);
          #pragma unroll
          for (int j = 0; j < 4; ++j) a3lo[j] = pkbf(xa[j], xb[j]); }
        p = gWd1 + (16 + i15) * 32 + ko;
        { f32x4 xa = *(const f32x4*)p, xb = *(const f32x4*)(p + 16);
          #pragma unroll
          for (int j = 0; j < 4; ++j) a3hi[j] = pkbf(xa[j], xb[j]); }
    }
    const short8 fW2lo  = __builtin_bit_cast(short8, (u32x4){a2lo[0], a2lo[1], a2lo[2], a2lo[3]});
    const short8 fW2hi  = __builtin_bit_cast(short8, (u32x4){a2hi[0], a2hi[1], a2hi[2], a2hi[3]});
    const short8 fWd1lo = __builtin_bit_cast(short8, (u32x4){a3lo[0], a3lo[1], a3lo[2], a3lo[3]});
    const short8 fWd1hi = __builtin_bit_cast(short8, (u32x4){a3hi[0], a3hi[1], a3hi[2], a3hi[3]});

    f32x2 w00, w01, w02, w03, w10, w11, w12, w13, w20, w21, w22, w23;
    {
        f32x4 xa, xb;
        xa = *(const f32x4*)(gWd2 + 0*32 + ko); xb = *(const f32x4*)(gWd2 + 0*32 + ko + 16);
        w00.x = xa[0]; w00.y = xb[0]; w01.x = xa[1]; w01.y = xb[1];
        w02.x = xa[2]; w02.y = xb[2]; w03.x = xa[3]; w03.y = xb[3];
        xa = *(const f32x4*)(gWd2 + 1*32 + ko); xb = *(const f32x4*)(gWd2 + 1*32 + ko + 16);
        w10.x = xa[0]; w10.y = xb[0]; w11.x = xa[1]; w11.y = xb[1];
        w12.x = xa[2]; w12.y = xb[2]; w13.x = xa[3]; w13.y = xb[3];
        xa = *(const f32x4*)(gWd2 + 2*32 + ko); xb = *(const f32x4*)(gWd2 + 2*32 + ko + 16);
        w20.x = xa[0]; w20.y = xb[0]; w21.x = xa[1]; w21.y = xb[1];
        w22.x = xa[2]; w22.y = xb[2]; w23.x = xa[3]; w23.y = xb[3];
    }
    const f32x4 cb1lo  = *(const f32x4*)(gb1  + ko);
    const f32x4 cb1hi  = *(const f32x4*)(gb1  + 16 + ko);
    const f32x4 cb2lo  = *(const f32x4*)(gb2  + ko);
    const f32x4 cb2hi  = *(const f32x4*)(gb2  + 16 + ko);
    const f32x4 cbd1lo = *(const f32x4*)(gbd1 + ko);
    const f32x4 cbd1hi = *(const f32x4*)(gbd1 + 16 + ko);

    // ---- GS + feat for all four rows (independent), one barrier ----
    const Rot RA = gs_feat(vin, win, rowA, &featlds[tid * 8]);
    const Rot RB = gs_feat(vin, win, rowB, &featlds[(256 + tid) * 8]);
    const Rot RC = gs_feat(vin, win, rowC, &featlds[(512 + tid) * 8]);
    const Rot RD = gs_feat(vin, win, rowD, &featlds[(768 + tid) * 8]);
    if (tid < 8) featlds[1024 * 8 + tid] = 0u;   // pad row for last set's overread
    __syncthreads();

    // ---- 16 independent tile-chains (4 sets x 4 tiles), all in registers ----
    float yA0, yA1, yA2, yB0, yB1, yB2, yC0, yC1, yC2, yD0, yD1, yD2;
    TILE_CHAIN(0,   yA0, yA1, yA2);
    TILE_CHAIN(256, yB0, yB1, yB2);
    TILE_CHAIN(512, yC0, yC1, yC2);
    TILE_CHAIN(768, yD0, yD1, yD2);

    const float bd20 = gbd2[0], bd21 = gbd2[1], bd22 = gbd2[2];
    const float gbs0 = gbias[0], gbs1 = gbias[1], gbs2 = gbias[2];
    yA0 += bd20; yA1 += bd21; yA2 += bd22;
    yB0 += bd20; yB1 += bd21; yB2 += bd22;
    yC0 += bd20; yC1 += bd21; yC2 += bd22;
    yD0 += bd20; yD1 += bd21; yD2 += bd22;

    EMIT_OUT(RA, yA0, yA1, yA2, rowA);
    EMIT_OUT(RB, yB0, yB1, yB2, rowB);
    EMIT_OUT(RC, yC0, yC1, yC2, rowC);
    EMIT_OUT(RD, yD0, yD1, yD2, rowD);
}

extern "C" void kernel_launch(void* const* d_in, const int* in_sizes, int n_in,
                              void* d_out, int out_size, void* d_ws, size_t ws_size,
                              hipStream_t stream) {
    const float* v    = (const float*)d_in[0];
    const float* w    = (const float*)d_in[1];
    const float* W1   = (const float*)d_in[2];
    const float* b1   = (const float*)d_in[3];
    const float* W2   = (const float*)d_in[4];
    const float* b2   = (const float*)d_in[5];
    const float* Wd1  = (const float*)d_in[6];
    const float* bd1  = (const float*)d_in[7];
    const float* Wd2  = (const float*)d_in[8];
    const float* bd2  = (const float*)d_in[9];
    const float* bias = (const float*)d_in[10];

    const int nrows = in_sizes[0] / 3;
    dim3 block(256);
    dim3 grid((nrows + 1023) / 1024);
    hipLaunchKernelGGL(aero_mfma, grid, block, 0, stream,
                       v, w, W1, b1, W2, b2, Wd1, bd1, Wd2, bd2, bias,
                       (float*)d_out, nrows);
}

// Round 16
// 133.656 us; speedup vs baseline: 1.0383x; 1.0383x over previous
//
#include <hip/hip_runtime.h>

typedef __attribute__((ext_vector_type(8))) short short8;
typedef __attribute__((ext_vector_type(4))) float f32x4;
typedef __attribute__((ext_vector_type(4))) unsigned int u32x4;

static __device__ __forceinline__ unsigned int fbits(float f) {
    union { float f; unsigned int u; } v; v.f = f; return v.u;
}
static __device__ __forceinline__ unsigned int pkbf(float lo, float hi) {
    return __builtin_amdgcn_perm(fbits(hi), fbits(lo), 0x07060302u);
}
static __device__ __forceinline__ float leaky(float x) { return fmaxf(x, 0.01f * x); }
static __device__ __forceinline__ float rsqrt_nr(float x) {
    const float r = __builtin_amdgcn_rsqf(x);
    return r * (1.5f - (0.5f * x) * (r * r));
}

// ROUND 16: r14 geometry (2 rows/lane -- r15 proved 4 is flat: ILP lever
// saturated) + two targeted changes:
//  (1) MANUAL STAGE-INTERLEAVE of sets A/B in one t-loop: issue A's MFMAs, B's
//      MFMAs, then A's epilogue (A drained behind B's issue), A's next MFMAs,
//      B's epilogue, ... -- an explicit 2-deep pipeline in source order. r15
//      showed sequential TILE_CHAIN blocks don't auto-interleave (wall 50 vs
//      busy 28: ~20us exposed chain latency).
//  (2) L4 ON MFMA: A = Wd2 rows zero-padded 3->16 (exact mirror of the verified
//      L1 zero-pad), bias bd2 as the C operand on quad-0 lanes. Output
//      y[16t+i15][r] lands in lane (i15, q=0) reg r (r<3); broadcast via
//      __shfl(acc[r], i15); owner lane keeps at t==quad. Replaces 12 pk + 6 add
//      + 6 shfl per tile-set; frees the 24-VGPR Wd2 pair bank.
// C-layout algebra and row ownership (wbase+16t+i15 == tid at t==quad) verified
// r10-r15 (absmax <= 1.4e-4 passing in every round).
//
// feat LDS: 513 rows x 32B; row r u32 j = bf16 pair (k=j lo, k=j+16 hi), only
// j<3 lo nonzero. quad>0 b128 overreads hit zeros / next row (finite) -- all
// k>=3 slots multiply ZERO A-weights.

struct Rot { float a0,a1,a2,c0,c1,c2,u0,u1,u2; };

static __device__ __forceinline__ Rot gs_feat(
    const float* __restrict__ vin, const float* __restrict__ win,
    int row, unsigned int* __restrict__ dst)
{
    const float v0 = vin[3*row+0], v1 = vin[3*row+1], v2 = vin[3*row+2];
    const float w0 = win[3*row+0], w1 = win[3*row+1], w2 = win[3*row+2];
    const float sv  = v0*v0 + v1*v1 + v2*v2;
    const float rnv = rsqrt_nr(sv);
    const float a0 = v0*rnv, a1 = v1*rnv, a2 = v2*rnv;            // v_on
    const float proj = w0*a0 + w1*a1 + w2*a2;
    const float o0 = w0 - proj*a0, o1 = w1 - proj*a1, o2 = w2 - proj*a2;
    const float sw  = o0*o0 + o1*o1 + o2*o2;
    const float rnw = rsqrt_nr(sw);
    const float c0 = o0*rnw, c1 = o1*rnw, c2 = o2*rnw;            // w_on
    const float u0 = a1*c2 - a2*c1;                               // u_on
    const float u1 = a2*c0 - a0*c2;
    const float u2 = a0*c1 - a1*c0;
    *(u32x4*)(dst)     = (u32x4){ fbits(sv*rnv) >> 16, fbits(proj) >> 16,
                                  fbits(sw*rnw) >> 16, 0u };
    *(u32x4*)(dst + 4) = (u32x4){ 0u, 0u, 0u, 0u };
    return {a0,a1,a2,c0,c1,c2,u0,u1,u2};
}

__global__ __launch_bounds__(256, 3) void aero_mfma(
    const float* __restrict__ vin, const float* __restrict__ win,
    const float* __restrict__ gW1, const float* __restrict__ gb1,
    const float* __restrict__ gW2, const float* __restrict__ gb2,
    const float* __restrict__ gWd1, const float* __restrict__ gbd1,
    const float* __restrict__ gWd2, const float* __restrict__ gbd2,
    const float* __restrict__ gbias,
    float* __restrict__ out, int nrows)
{
    __shared__ unsigned int featlds[513 * 8];   // 512 rows + 1 zero pad row

    const int tid   = threadIdx.x;
    const int i15   = tid & 15;
    const int quad  = (tid >> 4) & 3;
    const int wbase = tid & 192;               // wave's 64-row window (within a set)
    const int ko    = 4 * quad;

    const int base = blockIdx.x * 512;
    int rowA = base + tid;        if (rowA >= nrows) rowA = nrows - 1;
    int rowB = base + 256 + tid;  if (rowB >= nrows) rowB = nrows - 1;

    // ---- preamble: all weights -> VGPR fragments ----
    unsigned int a1lo[4] = {0,0,0,0}, a1hi[4] = {0,0,0,0};
    if (quad == 0) {
        #pragma unroll
        for (int j = 0; j < 3; ++j) {
            a1lo[j] = fbits(gW1[i15 * 3 + j]) >> 16;          // (W1, 0) pair
            a1hi[j] = fbits(gW1[(16 + i15) * 3 + j]) >> 16;
        }
    }
    const short8 fW1lo = __builtin_bit_cast(short8, (u32x4){a1lo[0], a1lo[1], a1lo[2], a1lo[3]});
    const short8 fW1hi = __builtin_bit_cast(short8, (u32x4){a1hi[0], a1hi[1], a1hi[2], a1hi[3]});

    unsigned int a2lo[4], a2hi[4], a3lo[4], a3hi[4];
    {
        const float* p;
        p = gW2 + i15 * 32 + ko;
        { f32x4 xa = *(const f32x4*)p, xb = *(const f32x4*)(p + 16);
          #pragma unroll
          for (int j = 0; j < 4; ++j) a2lo[j] = pkbf(xa[j], xb[j]); }
        p = gW2 + (16 + i15) * 32 + ko;
        { f32x4 xa = *(const f32x4*)p, xb = *(const f32x4*)(p + 16);
          #pragma unroll
          for (int j = 0; j < 4; ++j) a2hi[j] = pkbf(xa[j], xb[j]); }
        p = gWd1 + i15 * 32 + ko;
        { f32x4 xa = *(const f32x4*)p, xb = *(const f32x4*)(p + 16);
          #pragma unroll
          for (int j = 0; j < 4; ++j) a3lo[j] = pkbf(xa[j], xb[j]); }
        p = gWd1 + (16 + i15) * 32 + ko;
        { f32x4 xa = *(const f32x4*)p, xb = *(const f32x4*)(p + 16);
          #pragma unroll
          for (int j = 0; j < 4; ++j) a3hi[j] = pkbf(xa[j], xb[j]); }
    }
    const short8 fW2lo  = __builtin_bit_cast(short8, (u32x4){a2lo[0], a2lo[1], a2lo[2], a2lo[3]});
    const short8 fW2hi  = __builtin_bit_cast(short8, (u32x4){a2hi[0], a2hi[1], a2hi[2], a2hi[3]});
    const short8 fWd1lo = __builtin_bit_cast(short8, (u32x4){a3lo[0], a3lo[1], a3lo[2], a3lo[3]});
    const short8 fWd1hi = __builtin_bit_cast(short8, (u32x4){a3hi[0], a3hi[1], a3hi[2], a3hi[3]});

    // L4 A-frag: Wd2 rows m=i15<3, zero-padded to 16 (mirror of L1 zero-pad)
    unsigned int a4[4] = {0,0,0,0};
    if (i15 < 3) {
        const float* p4 = gWd2 + i15 * 32 + ko;
        #pragma unroll
        for (int j = 0; j < 4; ++j) a4[j] = pkbf(p4[j], p4[j + 16]);
    }
    const short8 fWd2 = __builtin_bit_cast(short8, (u32x4){a4[0], a4[1], a4[2], a4[3]});

    const f32x4 cb1lo  = *(const f32x4*)(gb1  + ko);
    const f32x4 cb1hi  = *(const f32x4*)(gb1  + 16 + ko);
    const f32x4 cb2lo  = *(const f32x4*)(gb2  + ko);
    const f32x4 cb2hi  = *(const f32x4*)(gb2  + 16 + ko);
    const f32x4 cbd1lo = *(const f32x4*)(gbd1 + ko);
    const f32x4 cbd1hi = *(const f32x4*)(gbd1 + 16 + ko);
    // L4 C operand: feature f = ko+r gets bd2[f] for f<3 (quad-0 lanes), else 0
    f32x4 cbd2 = {0.f, 0.f, 0.f, 0.f};
    if (quad == 0) { cbd2[0] = gbd2[0]; cbd2[1] = gbd2[1]; cbd2[2] = gbd2[2]; }

    // ---- GS + feat for both rows, one barrier ----
    const Rot RA = gs_feat(vin, win, rowA, &featlds[tid * 8]);
    const Rot RB = gs_feat(vin, win, rowB, &featlds[(256 + tid) * 8]);
    if (tid < 8) featlds[512 * 8 + tid] = 0u;   // pad row for set-B overread
    __syncthreads();

    // ---- fused L1..L4, sets A and B stage-interleaved (2-deep pipeline) ----
    float yA0 = 0.f, yA1 = 0.f, yA2 = 0.f, yB0 = 0.f, yB1 = 0.f, yB2 = 0.f;
    #pragma unroll
    for (int t = 0; t < 4; ++t) {
        const int roff = (wbase + 16 * t + i15) * 8 + ko;
        const u32x4 bfrA = *(const u32x4*)(&featlds[roff]);
        const u32x4 bfrB = *(const u32x4*)(&featlds[256 * 8 + roff]);
        const short8 ffA = __builtin_bit_cast(short8, bfrA);
        const short8 ffB = __builtin_bit_cast(short8, bfrB);

        // L1 issue: A then B (4 independent MFMAs back-to-back)
        const f32x4 z1loA = __builtin_amdgcn_mfma_f32_16x16x32_bf16(fW1lo, ffA, cb1lo, 0, 0, 0);
        const f32x4 z1hiA = __builtin_amdgcn_mfma_f32_16x16x32_bf16(fW1hi, ffA, cb1hi, 0, 0, 0);
        const f32x4 z1loB = __builtin_amdgcn_mfma_f32_16x16x32_bf16(fW1lo, ffB, cb1lo, 0, 0, 0);
        const f32x4 z1hiB = __builtin_amdgcn_mfma_f32_16x16x32_bf16(fW1hi, ffB, cb1hi, 0, 0, 0);

        // A epilogue (A's MFMAs drained behind B's issue) -> L2 A issue
        const float h1l0A = leaky(z1loA[0]), h1l1A = leaky(z1loA[1]);
        const float h1l2A = leaky(z1loA[2]), h1l3A = leaky(z1loA[3]);
        const float h1h0A = leaky(z1hiA[0]), h1h1A = leaky(z1hiA[1]);
        const float h1h2A = leaky(z1hiA[2]), h1h3A = leaky(z1hiA[3]);
        const short8 h1fA = __builtin_bit_cast(short8, (u32x4){
            pkbf(h1l0A, h1h0A), pkbf(h1l1A, h1h1A), pkbf(h1l2A, h1h2A), pkbf(h1l3A, h1h3A) });
        const f32x4 z2loA = __builtin_amdgcn_mfma_f32_16x16x32_bf16(fW2lo, h1fA, cb2lo, 0, 0, 0);
        const f32x4 z2hiA = __builtin_amdgcn_mfma_f32_16x16x32_bf16(fW2hi, h1fA, cb2hi, 0, 0, 0);

        // B epilogue -> L2 B issue
        const float h1l0B = leaky(z1loB[0]), h1l1B = leaky(z1loB[1]);
        const float h1l2B = leaky(z1loB[2]), h1l3B = leaky(z1loB[3]);
        const float h1h0B = leaky(z1hiB[0]), h1h1B = leaky(z1hiB[1]);
        const float h1h2B = leaky(z1hiB[2]), h1h3B = leaky(z1hiB[3]);
        const short8 h1fB = __builtin_bit_cast(short8, (u32x4){
            pkbf(h1l0B, h1h0B), pkbf(h1l1B, h1h1B), pkbf(h1l2B, h1h2B), pkbf(h1l3B, h1h3B) });
        const f32x4 z2loB = __builtin_amdgcn_mfma_f32_16x16x32_bf16(fW2lo, h1fB, cb2lo, 0, 0, 0);
        const f32x4 z2hiB = __builtin_amdgcn_mfma_f32_16x16x32_bf16(fW2hi, h1fB, cb2hi, 0, 0, 0);

        // A gate-epilogue -> L3 A issue
        const short8 h2fA = __builtin_bit_cast(short8, (u32x4){
            pkbf(leaky(z2loA[0]) * h1l0A, leaky(z2hiA[0]) * h1h0A),
            pkbf(leaky(z2loA[1]) * h1l1A, leaky(z2hiA[1]) * h1h1A),
            pkbf(leaky(z2loA[2]) * h1l2A, leaky(z2hiA[2]) * h1h2A),
            pkbf(leaky(z2loA[3]) * h1l3A, leaky(z2hiA[3]) * h1h3A) });
        const f32x4 z3loA = __builtin_amdgcn_mfma_f32_16x16x32_bf16(fWd1lo, h2fA, cbd1lo, 0, 0, 0);
        const f32x4 z3hiA = __builtin_amdgcn_mfma_f32_16x16x32_bf16(fWd1hi, h2fA, cbd1hi, 0, 0, 0);

        // B gate-epilogue -> L3 B issue
        const short8 h2fB = __builtin_bit_cast(short8, (u32x4){
            pkbf(leaky(z2loB[0]) * h1l0B, leaky(z2hiB[0]) * h1h0B),
            pkbf(leaky(z2loB[1]) * h1l1B, leaky(z2hiB[1]) * h1h1B),
            pkbf(leaky(z2loB[2]) * h1l2B, leaky(z2hiB[2]) * h1h2B),
            pkbf(leaky(z2loB[3]) * h1l3B, leaky(z2hiB[3]) * h1h3B) });
        const f32x4 z3loB = __builtin_amdgcn_mfma_f32_16x16x32_bf16(fWd1lo, h2fB, cbd1lo, 0, 0, 0);
        const f32x4 z3hiB = __builtin_amdgcn_mfma_f32_16x16x32_bf16(fWd1hi, h2fB, cbd1hi, 0, 0, 0);

        // A h3-epilogue -> L4 A (one MFMA, bias in C)
        const short8 h3fA = __builtin_bit_cast(short8, (u32x4){
            pkbf(leaky(z3loA[0]), leaky(z3hiA[0])),
            pkbf(leaky(z3loA[1]), leaky(z3hiA[1])),
            pkbf(leaky(z3loA[2]), leaky(z3hiA[2])),
            pkbf(leaky(z3loA[3]), leaky(z3hiA[3])) });
        const f32x4 yAacc = __builtin_amdgcn_mfma_f32_16x16x32_bf16(fWd2, h3fA, cbd2, 0, 0, 0);

        // B h3-epilogue -> L4 B
        const short8 h3fB = __builtin_bit_cast(short8, (u32x4){
            pkbf(leaky(z3loB[0]), leaky(z3hiB[0])),
            pkbf(leaky(z3loB[1]), leaky(z3hiB[1])),
            pkbf(leaky(z3loB[2]), leaky(z3hiB[2])),
            pkbf(leaky(z3loB[3]), leaky(z3hiB[3])) });
        const f32x4 yBacc = __builtin_amdgcn_mfma_f32_16x16x32_bf16(fWd2, h3fB, cbd2, 0, 0, 0);

        // y broadcast: y[16t+i15][r] lives in lane (i15, q=0) reg r
        const float sA0 = __shfl(yAacc[0], i15);
        const float sA1 = __shfl(yAacc[1], i15);
        const float sA2 = __shfl(yAacc[2], i15);
        const float sB0 = __shfl(yBacc[0], i15);
        const float sB1 = __shfl(yBacc[1], i15);
        const float sB2 = __shfl(yBacc[2], i15);
        if (quad == t) {
            yA0 = sA0; yA1 = sA1; yA2 = sA2;
            yB0 = sB0; yB1 = sB1; yB2 = sB2;
        }
    }

    const float gbs0 = gbias[0], gbs1 = gbias[1], gbs2 = gbias[2];
    out[3*rowA + 0] = fmaf(RA.a0, yA0, fmaf(RA.c0, yA1, fmaf(RA.u0, yA2, gbs0)));
    out[3*rowA + 1] = fmaf(RA.a1, yA0, fmaf(RA.c1, yA1, fmaf(RA.u1, yA2, gbs1)));
    out[3*rowA + 2] = fmaf(RA.a2, yA0, fmaf(RA.c2, yA1, fmaf(RA.u2, yA2, gbs2)));
    out[3*rowB + 0] = fmaf(RB.a0, yB0, fmaf(RB.c0, yB1, fmaf(RB.u0, yB2, gbs0)));
    out[3*rowB + 1] = fmaf(RB.a1, yB0, fmaf(RB.c1, yB1, fmaf(RB.u1, yB2, gbs1)));
    out[3*rowB + 2] = fmaf(RB.a2, yB0, fmaf(RB.c2, yB1, fmaf(RB.u2, yB2, gbs2)));
}

extern "C" void kernel_launch(void* const* d_in, const int* in_sizes, int n_in,
                              void* d_out, int out_size, void* d_ws, size_t ws_size,
                              hipStream_t stream) {
    const float* v    = (const float*)d_in[0];
    const float* w    = (const float*)d_in[1];
    const float* W1   = (const float*)d_in[2];
    const float* b1   = (const float*)d_in[3];
    const float* W2   = (const float*)d_in[4];
    const float* b2   = (const float*)d_in[5];
    const float* Wd1  = (const float*)d_in[6];
    const float* bd1  = (const float*)d_in[7];
    const float* Wd2  = (const float*)d_in[8];
    const float* bd2  = (const float*)d_in[9];
    const float* bias = (const float*)d_in[10];

    const int nrows = in_sizes[0] / 3;
    dim3 block(256);
    dim3 grid((nrows + 511) / 512);
    hipLaunchKernelGGL(aero_mfma, grid, block, 0, stream,
                       v, w, W1, b1, W2, b2, Wd1, bd1, Wd2, bd2, bias,
                       (float*)d_out, nrows);
}

// Round 17
// 132.901 us; speedup vs baseline: 1.0442x; 1.0057x over previous
//
#include <hip/hip_runtime.h>

typedef __attribute__((ext_vector_type(8))) short short8;
typedef __attribute__((ext_vector_type(4))) float f32x4;
typedef __attribute__((ext_vector_type(4))) unsigned int u32x4;

static __device__ __forceinline__ unsigned int fbits(float f) {
    union { float f; unsigned int u; } v; v.f = f; return v.u;
}
static __device__ __forceinline__ unsigned int pkbf(float lo, float hi) {
    return __builtin_amdgcn_perm(fbits(hi), fbits(lo), 0x07060302u);
}
static __device__ __forceinline__ float leaky(float x) { return fmaxf(x, 0.01f * x); }
static __device__ __forceinline__ float rsqrt_nr(float x) {
    const float r = __builtin_amdgcn_rsqf(x);
    return r * (1.5f - (0.5f * x) * (r * r));
}

// ROUND 17: 4-SET MANUAL STAGE-INTERLEAVE. r16 proved the mechanism: 2 manually
// interleaved chains won 10% (50 -> 45.3) where r15's 4 SEQUENTIAL chains were
// flat -- the compiler doesn't interleave across big blocks; source order is the
// pipeline control. This round runs 4 sets through the interleave: each MFMA's
// consumer sits ~3 sets' issue (~60 VALU + 6 MFMA) downstream, doubling latency
// coverage again. Per-row busy work unchanged. launch_bounds (256,2): VGPR room
// so no spill path (r4 lesson); achieved occupancy is already ~2 blocks/CU.
// If flat vs r16: pipeline is covered, remaining gap is structural -> declare.
//
// Structure (verified r10-r16, absmax <= 4.2e-4 passing): all 4 layers on MFMA
// via swapped operands (z^T = mfma(A=W, B=h^T)); C-layout output slots == next
// B-frag slots -> register chain; L1 K-padded 3->32 and L4 M-padded 3->16 with
// ZERO weights; biases are MFMA C operands; y broadcast from quad-0 lanes via
// __shfl(acc[r], i15), owner keeps at t==quad (wbase+16t+i15 == tid).
// feat LDS: 1025 rows x 32B, u32 j = bf16 pair (k=j lo, k=j+16 hi), j<3 lo only;
// quad>0 overreads hit zeros/next rows (finite), annihilated by zero A-weights.

struct Rot { float a0,a1,a2,c0,c1,c2,u0,u1,u2; };

static __device__ __forceinline__ Rot gs_feat(
    const float* __restrict__ vin, const float* __restrict__ win,
    int row, unsigned int* __restrict__ dst)
{
    const float v0 = vin[3*row+0], v1 = vin[3*row+1], v2 = vin[3*row+2];
    const float w0 = win[3*row+0], w1 = win[3*row+1], w2 = win[3*row+2];
    const float sv  = v0*v0 + v1*v1 + v2*v2;
    const float rnv = rsqrt_nr(sv);
    const float a0 = v0*rnv, a1 = v1*rnv, a2 = v2*rnv;            // v_on
    const float proj = w0*a0 + w1*a1 + w2*a2;
    const float o0 = w0 - proj*a0, o1 = w1 - proj*a1, o2 = w2 - proj*a2;
    const float sw  = o0*o0 + o1*o1 + o2*o2;
    const float rnw = rsqrt_nr(sw);
    const float c0 = o0*rnw, c1 = o1*rnw, c2 = o2*rnw;            // w_on
    const float u0 = a1*c2 - a2*c1;                               // u_on
    const float u1 = a2*c0 - a0*c2;
    const float u2 = a0*c1 - a1*c0;
    *(u32x4*)(dst)     = (u32x4){ fbits(sv*rnv) >> 16, fbits(proj) >> 16,
                                  fbits(sw*rnw) >> 16, 0u };
    *(u32x4*)(dst + 4) = (u32x4){ 0u, 0u, 0u, 0u };
    return {a0,a1,a2,c0,c1,c2,u0,u1,u2};
}

// -------- pipeline stage macros (token-pasted per set S) --------
#define STAGE_LOAD(S, LB)                                                          \
    const u32x4 bfr##S = *(const u32x4*)(&featlds[(LB) * 8 + roff]);               \
    const short8 ff##S = __builtin_bit_cast(short8, bfr##S);

#define STAGE_L1(S)                                                                \
    const f32x4 z1lo##S = __builtin_amdgcn_mfma_f32_16x16x32_bf16(fW1lo, ff##S, cb1lo, 0, 0, 0); \
    const f32x4 z1hi##S = __builtin_amdgcn_mfma_f32_16x16x32_bf16(fW1hi, ff##S, cb1hi, 0, 0, 0);

#define STAGE_EPI1_L2(S)                                                           \
    const float h1l0##S = leaky(z1lo##S[0]), h1l1##S = leaky(z1lo##S[1]);          \
    const float h1l2##S = leaky(z1lo##S[2]), h1l3##S = leaky(z1lo##S[3]);          \
    const float h1h0##S = leaky(z1hi##S[0]), h1h1##S = leaky(z1hi##S[1]);          \
    const float h1h2##S = leaky(z1hi##S[2]), h1h3##S = leaky(z1hi##S[3]);          \
    const short8 h1f##S = __builtin_bit_cast(short8, (u32x4){                      \
        pkbf(h1l0##S, h1h0##S), pkbf(h1l1##S, h1h1##S),                            \
        pkbf(h1l2##S, h1h2##S), pkbf(h1l3##S, h1h3##S) });                         \
    const f32x4 z2lo##S = __builtin_amdgcn_mfma_f32_16x16x32_bf16(fW2lo, h1f##S, cb2lo, 0, 0, 0); \
    const f32x4 z2hi##S = __builtin_amdgcn_mfma_f32_16x16x32_bf16(fW2hi, h1f##S, cb2hi, 0, 0, 0);

#define STAGE_GATE_L3(S)                                                           \
    const short8 h2f##S = __builtin_bit_cast(short8, (u32x4){                      \
        pkbf(leaky(z2lo##S[0]) * h1l0##S, leaky(z2hi##S[0]) * h1h0##S),            \
        pkbf(leaky(z2lo##S[1]) * h1l1##S, leaky(z2hi##S[1]) * h1h1##S),            \
        pkbf(leaky(z2lo##S[2]) * h1l2##S, leaky(z2hi##S[2]) * h1h2##S),            \
        pkbf(leaky(z2lo##S[3]) * h1l3##S, leaky(z2hi##S[3]) * h1h3##S) });         \
    const f32x4 z3lo##S = __builtin_amdgcn_mfma_f32_16x16x32_bf16(fWd1lo, h2f##S, cbd1lo, 0, 0, 0); \
    const f32x4 z3hi##S = __builtin_amdgcn_mfma_f32_16x16x32_bf16(fWd1hi, h2f##S, cbd1hi, 0, 0, 0);

#define STAGE_H3_L4(S)                                                             \
    const short8 h3f##S = __builtin_bit_cast(short8, (u32x4){                      \
        pkbf(leaky(z3lo##S[0]), leaky(z3hi##S[0])),                                \
        pkbf(leaky(z3lo##S[1]), leaky(z3hi##S[1])),                                \
        pkbf(leaky(z3lo##S[2]), leaky(z3hi##S[2])),                                \
        pkbf(leaky(z3lo##S[3]), leaky(z3hi##S[3])) });                             \
    const f32x4 yacc##S = __builtin_amdgcn_mfma_f32_16x16x32_bf16(fWd2, h3f##S, cbd2, 0, 0, 0);

#define STAGE_BCAST(S)                                                             \
    {                                                                              \
        const float s0 = __shfl(yacc##S[0], i15);                                  \
        const float s1 = __shfl(yacc##S[1], i15);                                  \
        const float s2 = __shfl(yacc##S[2], i15);                                  \
        if (quad == t) { y##S##0 = s0; y##S##1 = s1; y##S##2 = s2; }               \
    }

#define EMIT_OUT(R, Y0, Y1, Y2, ROW)                                               \
    out[3*(ROW) + 0] = fmaf(R.a0, Y0, fmaf(R.c0, Y1, fmaf(R.u0, Y2, gbs0)));       \
    out[3*(ROW) + 1] = fmaf(R.a1, Y0, fmaf(R.c1, Y1, fmaf(R.u1, Y2, gbs1)));       \
    out[3*(ROW) + 2] = fmaf(R.a2, Y0, fmaf(R.c2, Y1, fmaf(R.u2, Y2, gbs2)));

__global__ __launch_bounds__(256, 2) void aero_mfma(
    const float* __restrict__ vin, const float* __restrict__ win,
    const float* __restrict__ gW1, const float* __restrict__ gb1,
    const float* __restrict__ gW2, const float* __restrict__ gb2,
    const float* __restrict__ gWd1, const float* __restrict__ gbd1,
    const float* __restrict__ gWd2, const float* __restrict__ gbd2,
    const float* __restrict__ gbias,
    float* __restrict__ out, int nrows)
{
    __shared__ unsigned int featlds[1025 * 8];   // 1024 rows + 1 zero pad row

    const int tid   = threadIdx.x;
    const int i15   = tid & 15;
    const int quad  = (tid >> 4) & 3;
    const int wbase = tid & 192;               // wave's 64-row window (within a set)
    const int ko    = 4 * quad;

    const int base = blockIdx.x * 1024;
    int rowA = base + tid;        if (rowA >= nrows) rowA = nrows - 1;
    int rowB = base + 256 + tid;  if (rowB >= nrows) rowB = nrows - 1;
    int rowC = base + 512 + tid;  if (rowC >= nrows) rowC = nrows - 1;
    int rowD = base + 768 + tid;  if (rowD >= nrows) rowD = nrows - 1;

    // ---- preamble: all weights -> VGPR fragments (once, amortized 4x) ----
    unsigned int a1lo[4] = {0,0,0,0}, a1hi[4] = {0,0,0,0};
    if (quad == 0) {
        #pragma unroll
        for (int j = 0; j < 3; ++j) {
            a1lo[j] = fbits(gW1[i15 * 3 + j]) >> 16;          // (W1, 0) pair
            a1hi[j] = fbits(gW1[(16 + i15) * 3 + j]) >> 16;
        }
    }
    const short8 fW1lo = __builtin_bit_cast(short8, (u32x4){a1lo[0], a1lo[1], a1lo[2], a1lo[3]});
    const short8 fW1hi = __builtin_bit_cast(short8, (u32x4){a1hi[0], a1hi[1], a1hi[2], a1hi[3]});

    unsigned int a2lo[4], a2hi[4], a3lo[4], a3hi[4];
    {
        const float* p;
        p = gW2 + i15 * 32 + ko;
        { f32x4 xa = *(const f32x4*)p, xb = *(const f32x4*)(p + 16);
          #pragma unroll
          for (int j = 0; j < 4; ++j) a2lo[j] = pkbf(xa[j], xb[j]); }
        p = gW2 + (16 + i15) * 32 + ko;
        { f32x4 xa = *(const f32x4*)p, xb = *(const f32x4*)(p + 16);
          #pragma unroll
          for (int j = 0; j < 4; ++j) a2hi[j] = pkbf(xa[j], xb[j]); }
        p = gWd1 + i15 * 32 + ko;
        { f32x4 xa = *(const f32x4*)p, xb = *(const f32x4*)(p + 16);
          #pragma unroll
          for (int j = 0; j < 4; ++j) a3lo[j] = pkbf(xa[j], xb[j]); }
        p = gWd1 + (16 + i15) * 32 + ko;
        { f32x4 xa = *(const f32x4*)p, xb = *(const f32x4*)(p + 16);
          #pragma unroll
          for (int j = 0; j < 4; ++j) a3hi[j] = pkbf(xa[j], xb[j]); }
    }
    const short8 fW2lo  = __builtin_bit_cast(short8, (u32x4){a2lo[0], a2lo[1], a2lo[2], a2lo[3]});
    const short8 fW2hi  = __builtin_bit_cast(short8, (u32x4){a2hi[0], a2hi[1], a2hi[2], a2hi[3]});
    const short8 fWd1lo = __builtin_bit_cast(short8, (u32x4){a3lo[0], a3lo[1], a3lo[2], a3lo[3]});
    const short8 fWd1hi = __builtin_bit_cast(short8, (u32x4){a3hi[0], a3hi[1], a3hi[2], a3hi[3]});

    // L4 A-frag: Wd2 rows m=i15<3, zero-padded to 16
    unsigned int a4[4] = {0,0,0,0};
    if (i15 < 3) {
        const float* p4 = gWd2 + i15 * 32 + ko;
        #pragma unroll
        for (int j = 0; j < 4; ++j) a4[j] = pkbf(p4[j], p4[j + 16]);
    }
    const short8 fWd2 = __builtin_bit_cast(short8, (u32x4){a4[0], a4[1], a4[2], a4[3]});

    const f32x4 cb1lo  = *(const f32x4*)(gb1  + ko);
    const f32x4 cb1hi  = *(const f32x4*)(gb1  + 16 + ko);
    const f32x4 cb2lo  = *(const f32x4*)(gb2  + ko);
    const f32x4 cb2hi  = *(const f32x4*)(gb2  + 16 + ko);
    const f32x4 cbd1lo = *(const f32x4*)(gbd1 + ko);
    const f32x4 cbd1hi = *(const f32x4*)(gbd1 + 16 + ko);
    f32x4 cbd2 = {0.f, 0.f, 0.f, 0.f};
    if (quad == 0) { cbd2[0] = gbd2[0]; cbd2[1] = gbd2[1]; cbd2[2] = gbd2[2]; }

    // ---- GS + feat for all four rows, one barrier ----
    const Rot RA = gs_feat(vin, win, rowA, &featlds[tid * 8]);
    const Rot RB = gs_feat(vin, win, rowB, &featlds[(256 + tid) * 8]);
    const Rot RC = gs_feat(vin, win, rowC, &featlds[(512 + tid) * 8]);
    const Rot RD = gs_feat(vin, win, rowD, &featlds[(768 + tid) * 8]);
    if (tid < 8) featlds[1024 * 8 + tid] = 0u;   // pad row for last set's overread
    __syncthreads();

    // ---- fused L1..L4, 4 sets stage-interleaved (4-deep pipeline) ----
    float yA0 = 0.f, yA1 = 0.f, yA2 = 0.f, yB0 = 0.f, yB1 = 0.f, yB2 = 0.f;
    float yC0 = 0.f, yC1 = 0.f, yC2 = 0.f, yD0 = 0.f, yD1 = 0.f, yD2 = 0.f;
    #pragma unroll
    for (int t = 0; t < 4; ++t) {
        const int roff = (wbase + 16 * t + i15) * 8 + ko;
        STAGE_LOAD(A, 0)
        STAGE_LOAD(B, 256)
        STAGE_LOAD(C, 512)
        STAGE_LOAD(D, 768)

        STAGE_L1(A) STAGE_L1(B) STAGE_L1(C) STAGE_L1(D)

        STAGE_EPI1_L2(A) STAGE_EPI1_L2(B) STAGE_EPI1_L2(C) STAGE_EPI1_L2(D)

        STAGE_GATE_L3(A) STAGE_GATE_L3(B) STAGE_GATE_L3(C) STAGE_GATE_L3(D)

        STAGE_H3_L4(A) STAGE_H3_L4(B) STAGE_H3_L4(C) STAGE_H3_L4(D)

        STAGE_BCAST(A) STAGE_BCAST(B) STAGE_BCAST(C) STAGE_BCAST(D)
    }

    const float gbs0 = gbias[0], gbs1 = gbias[1], gbs2 = gbias[2];
    EMIT_OUT(RA, yA0, yA1, yA2, rowA);
    EMIT_OUT(RB, yB0, yB1, yB2, rowB);
    EMIT_OUT(RC, yC0, yC1, yC2, rowC);
    EMIT_OUT(RD, yD0, yD1, yD2, rowD);
}

extern "C" void kernel_launch(void* const* d_in, const int* in_sizes, int n_in,
                              void* d_out, int out_size, void* d_ws, size_t ws_size,
                              hipStream_t stream) {
    const float* v    = (const float*)d_in[0];
    const float* w    = (const float*)d_in[1];
    const float* W1   = (const float*)d_in[2];
    const float* b1   = (const float*)d_in[3];
    const float* W2   = (const float*)d_in[4];
    const float* b2   = (const float*)d_in[5];
    const float* Wd1  = (const float*)d_in[6];
    const float* bd1  = (const float*)d_in[7];
    const float* Wd2  = (const float*)d_in[8];
    const float* bd2  = (const float*)d_in[9];
    const float* bias = (const float*)d_in[10];

    const int nrows = in_sizes[0] / 3;
    dim3 block(256);
    dim3 grid((nrows + 1023) / 1024);
    hipLaunchKernelGGL(aero_mfma, grid, block, 0, stream,
                       v, w, W1, b1, W2, b2, Wd1, bd1, Wd2, bd2, bias,
                       (float*)d_out, nrows);
}